// Round 1
// baseline (133.147 us; speedup 1.0000x reference)
//
#include <hip/hip_runtime.h>
#include <math.h>

#define BB 4
#define SS 16384
#define NN 1024
#define DD 64
#define MW 32   // mask words per row = NN/32

__device__ __forceinline__ float wave_sum(float v) {
    #pragma unroll
    for (int off = 32; off > 0; off >>= 1) v += __shfl_xor(v, off, 64);
    return v;
}
__device__ __forceinline__ float wave_max(float v) {
    #pragma unroll
    for (int off = 32; off > 0; off >>= 1) v = fmaxf(v, __shfl_xor(v, off, 64));
    return v;
}
__device__ __forceinline__ int wave_sum_i(int v) {
    #pragma unroll
    for (int off = 32; off > 0; off >>= 1) v += __shfl_xor(v, off, 64);
    return v;
}

// One wave (64 lanes) per flow; lane = feature. Scatter-add features at dst,
// set symmetric adjacency bits.
__global__ __launch_bounds__(256) void scatter_kernel(
        const float* __restrict__ ff, const int* __restrict__ src_ips,
        const int* __restrict__ dst_ips, float* __restrict__ node,
        unsigned int* __restrict__ mask) {
    int tid  = blockIdx.x * 256 + threadIdx.x;
    int flow = tid >> 6;
    int lane = tid & 63;
    if (flow >= BB * SS) return;
    int b   = flow >> 14;                 // SS = 2^14
    int dst = dst_ips[flow];
    int src = src_ips[flow];
    atomicAdd(node + ((b << 10) + dst) * DD + lane, ff[flow * DD + lane]);
    if (lane == 0) {
        unsigned int* mb = mask + (size_t)b * NN * MW;
        atomicOr(mb + src * MW + (dst >> 5), 1u << (dst & 31));
        atomicOr(mb + dst * MW + (src >> 5), 1u << (src & 31));
    }
}

// One wave per node-row: h = normalize(node); Wh = h@W; f1 = Wh.a1; f2 = Wh.a2
__global__ __launch_bounds__(256) void transform_kernel(
        const float* __restrict__ node, const float* __restrict__ W,
        const float* __restrict__ a1, const float* __restrict__ a2,
        float* __restrict__ Wh, float* __restrict__ f1, float* __restrict__ f2) {
    __shared__ float Ws[DD * DD];
    __shared__ float hs[4][DD];
    __shared__ float a1s[DD], a2s[DD];
    int t = threadIdx.x;
    for (int i = t; i < DD * DD; i += 256) Ws[i] = W[i];
    if (t < DD) { a1s[t] = a1[t]; a2s[t] = a2[t]; }
    __syncthreads();
    int wave = t >> 6, lane = t & 63;
    int row = blockIdx.x * 4 + wave;      // [0, BB*NN)
    float v  = node[row * DD + lane];
    float s2 = wave_sum(v * v);
    float nrm = fmaxf(sqrtf(s2), 1e-12f);
    hs[wave][lane] = v / nrm;
    __syncthreads();
    float acc = 0.f;
    #pragma unroll 8
    for (int k = 0; k < DD; ++k)
        acc = fmaf(hs[wave][k], Ws[k * DD + lane], acc);
    Wh[row * DD + lane] = acc;
    float p1 = wave_sum(acc * a1s[lane]);
    float p2 = wave_sum(acc * a2s[lane]);
    if (lane == 0) { f1[row] = p1; f2[row] = p2; }
}

// One wave per output row i: sparse masked softmax over neighbors, then
// out[i] = elu(sum_j attn_ij * Wh[j]).  lane = feature d in phase 2.
__global__ __launch_bounds__(256) void attn_kernel(
        const unsigned int* __restrict__ mask, const float* __restrict__ f1,
        const float* __restrict__ f2, const float* __restrict__ Wh,
        float* __restrict__ out) {
    __shared__ unsigned int ms[4][MW];
    int t = threadIdx.x;
    int wave = t >> 6, lane = t & 63;
    int row = blockIdx.x * 4 + wave;      // [0, BB*NN)
    int b = row >> 10;
    const unsigned int* mrow = mask + (size_t)row * MW;
    if (lane < MW) ms[wave][lane] = mrow[lane];
    __syncthreads();
    const float* f2b = f2 + b * NN;
    const float* Whb = Wh + (size_t)(b << 10) * DD;
    float f1i = f1[row];

    int cnt = (lane < MW) ? __popc(ms[wave][lane]) : 0;
    cnt = wave_sum_i(cnt);

    // phase 1: max and sum of exp over masked entries (lane strides j)
    float m = -INFINITY;
    #pragma unroll
    for (int tt = 0; tt < 16; ++tt) {
        int j = lane + (tt << 6);
        if (ms[wave][j >> 5] & (1u << (j & 31))) {
            float e = f1i + f2b[j];
            e = (e >= 0.f) ? e : 0.2f * e;
            m = fmaxf(m, e);
        }
    }
    m = wave_max(m);
    float lsum = 0.f;
    #pragma unroll
    for (int tt = 0; tt < 16; ++tt) {
        int j = lane + (tt << 6);
        if (ms[wave][j >> 5] & (1u << (j & 31))) {
            float e = f1i + f2b[j];
            e = (e >= 0.f) ? e : 0.2f * e;
            lsum += __expf(e - m);
        }
    }
    lsum = wave_sum(lsum);

    // phase 2: lane = feature; iterate set bits (wave-uniform loop)
    float acc = 0.f;
    if (cnt > 0) {
        for (int w = 0; w < MW; ++w) {
            unsigned int bits = ms[wave][w];
            while (bits) {
                int j = (w << 5) + (__ffs(bits) - 1);
                bits &= bits - 1;
                float e = f1i + f2b[j];
                e = (e >= 0.f) ? e : 0.2f * e;
                float p = __expf(e - m);
                acc = fmaf(p, Whb[j * DD + lane], acc);
            }
        }
        acc /= lsum;
    } else {
        // all-masked row: softmax of equal NEG_BIG = uniform 1/N over ALL j
        for (int j = 0; j < NN; ++j) acc += Whb[j * DD + lane];
        acc *= (1.f / NN);
    }
    float o = (acc > 0.f) ? acc : expm1f(acc);
    out[row * DD + lane] = o;
}

extern "C" void kernel_launch(void* const* d_in, const int* in_sizes, int n_in,
                              void* d_out, int out_size, void* d_ws, size_t ws_size,
                              hipStream_t stream) {
    const float* ff      = (const float*)d_in[0];
    const int*   src_ips = (const int*)d_in[1];
    const int*   dst_ips = (const int*)d_in[2];
    // d_in[3] flow_volumes, d_in[4] emb, d_in[5..8] MLP params: provably only
    // affect adj through strictly-positive values -> only the >0 mask matters.
    const float* W  = (const float*)d_in[9];
    const float* a1 = (const float*)d_in[10];
    const float* a2 = (const float*)d_in[11];
    float* out = (float*)d_out;

    char* ws = (char*)d_ws;
    float* node = (float*)ws;                              // 1 MB
    float* Wh   = (float*)(ws + (1 << 20));                // 1 MB
    float* f1   = (float*)(ws + (2 << 20));                // 16 KB
    float* f2   = (float*)(ws + (2 << 20) + (1 << 14));    // 16 KB
    unsigned int* mask = (unsigned int*)(ws + (2 << 20) + (2 << 14)); // 512 KB

    hipMemsetAsync(node, 0, (size_t)BB * NN * DD * sizeof(float), stream);
    hipMemsetAsync(mask, 0, (size_t)BB * NN * MW * sizeof(unsigned int), stream);

    scatter_kernel<<<BB * SS / 4, 256, 0, stream>>>(ff, src_ips, dst_ips, node, mask);
    transform_kernel<<<BB * NN / 4, 256, 0, stream>>>(node, W, a1, a2, Wh, f1, f2);
    attn_kernel<<<BB * NN / 4, 256, 0, stream>>>(mask, f1, f2, Wh, out);
}

// Round 2
// 124.683 us; speedup vs baseline: 1.0679x; 1.0679x over previous
//
#include <hip/hip_runtime.h>
#include <math.h>

#define BB 4
#define SS 16384
#define NN 1024
#define DD 64
#define MW 32    // mask words per row = NN/32
#define CAP 256  // bucket capacity per (b,node); Poisson(16) => overflow P ~ 0

__device__ __forceinline__ float wave_sum(float v) {
    #pragma unroll
    for (int off = 32; off > 0; off >>= 1) v += __shfl_xor(v, off, 64);
    return v;
}
__device__ __forceinline__ float wave_max(float v) {
    #pragma unroll
    for (int off = 32; off > 0; off >>= 1) v = fmaxf(v, __shfl_xor(v, off, 64));
    return v;
}
__device__ __forceinline__ int wave_sum_i(int v) {
    #pragma unroll
    for (int off = 32; off > 0; off >>= 1) v += __shfl_xor(v, off, 64);
    return v;
}

// 1 thread per flow: bucket the flow id by (b,dst), set symmetric adj bits.
__global__ __launch_bounds__(256) void build_kernel(
        const int* __restrict__ src_ips, const int* __restrict__ dst_ips,
        int* __restrict__ count, int* __restrict__ bucket,
        unsigned int* __restrict__ mask) {
    int tid = blockIdx.x * 256 + threadIdx.x;   // global flow id, [0, BB*SS)
    int b   = tid >> 14;                        // SS = 2^14
    int dst = dst_ips[tid];
    int src = src_ips[tid];
    int row = (b << 10) + dst;
    int pos = atomicAdd(count + row, 1);
    if (pos < CAP) bucket[row * CAP + pos] = tid;
    unsigned int* mb = mask + (size_t)b * NN * MW;
    atomicOr(mb + src * MW + (dst >> 5), 1u << (dst & 31));
    atomicOr(mb + dst * MW + (src >> 5), 1u << (src & 31));
}

// One wave per (b,node): gather-sum flow rows, normalize, Wh = h@W, f1, f2.
__global__ __launch_bounds__(256) void gather_transform_kernel(
        const float* __restrict__ ff, const int* __restrict__ count,
        const int* __restrict__ bucket, const float* __restrict__ W,
        const float* __restrict__ a1, const float* __restrict__ a2,
        float* __restrict__ Wh, float* __restrict__ f1, float* __restrict__ f2) {
    __shared__ float Ws[DD * DD];
    __shared__ float hs[4][DD];
    __shared__ float a1s[DD], a2s[DD];
    int t = threadIdx.x;
    for (int i = t; i < DD * DD; i += 256) Ws[i] = W[i];
    if (t < DD) { a1s[t] = a1[t]; a2s[t] = a2[t]; }
    int wave = t >> 6, lane = t & 63;
    int row = blockIdx.x * 4 + wave;            // [0, BB*NN)

    int cnt = min(count[row], CAP);
    const int* bk = bucket + (size_t)row * CAP;
    float acc = 0.f;
    for (int base = 0; base < cnt; base += 64) {
        int fid = 0;
        if (base + lane < cnt) fid = bk[base + lane];
        int lim = min(64, cnt - base);
        for (int i = 0; i < lim; ++i) {
            int flow = __shfl(fid, i, 64);
            acc += ff[(size_t)flow * DD + lane];
        }
    }
    float nrm = fmaxf(sqrtf(wave_sum(acc * acc)), 1e-12f);
    __syncthreads();                            // Ws/a1s/a2s ready
    hs[wave][lane] = acc / nrm;
    __syncthreads();                            // hs visible across lanes
    float whl = 0.f;
    #pragma unroll 8
    for (int k = 0; k < DD; ++k)
        whl = fmaf(hs[wave][k], Ws[k * DD + lane], whl);
    Wh[row * DD + lane] = whl;
    float p1 = wave_sum(whl * a1s[lane]);
    float p2 = wave_sum(whl * a2s[lane]);
    if (lane == 0) { f1[row] = p1; f2[row] = p2; }
}

// One wave per output row i: sparse masked softmax over neighbors, then
// out[i] = elu(sum_j attn_ij * Wh[j]).  lane = feature d in phase 2.
__global__ __launch_bounds__(256) void attn_kernel(
        const unsigned int* __restrict__ mask, const float* __restrict__ f1,
        const float* __restrict__ f2, const float* __restrict__ Wh,
        float* __restrict__ out) {
    __shared__ unsigned int ms[4][MW];
    int t = threadIdx.x;
    int wave = t >> 6, lane = t & 63;
    int row = blockIdx.x * 4 + wave;            // [0, BB*NN)
    int b = row >> 10;
    const unsigned int* mrow = mask + (size_t)row * MW;
    if (lane < MW) ms[wave][lane] = mrow[lane];
    __syncthreads();
    const float* f2b = f2 + b * NN;
    const float* Whb = Wh + (size_t)(b << 10) * DD;
    float f1i = f1[row];

    int cnt = (lane < MW) ? __popc(ms[wave][lane]) : 0;
    cnt = wave_sum_i(cnt);

    // phase 1: leaky-relu scores in registers (16 j's per lane), max then sum
    float ev[16];
    float m = -INFINITY;
    #pragma unroll
    for (int tt = 0; tt < 16; ++tt) {
        int j = lane + (tt << 6);
        ev[tt] = -INFINITY;
        if (ms[wave][j >> 5] & (1u << (j & 31))) {
            float e = f1i + f2b[j];
            ev[tt] = (e >= 0.f) ? e : 0.2f * e;
            m = fmaxf(m, ev[tt]);
        }
    }
    m = wave_max(m);
    float lsum = 0.f;
    #pragma unroll
    for (int tt = 0; tt < 16; ++tt)
        if (ev[tt] > -INFINITY) lsum += __expf(ev[tt] - m);
    lsum = wave_sum(lsum);

    // phase 2: lane = feature; iterate set bits (wave-uniform loop)
    float acc = 0.f;
    if (cnt > 0) {
        for (int w = 0; w < MW; ++w) {
            unsigned int bits = ms[wave][w];
            while (bits) {
                int j = (w << 5) + (__ffs(bits) - 1);
                bits &= bits - 1;
                float e = f1i + f2b[j];
                e = (e >= 0.f) ? e : 0.2f * e;
                float p = __expf(e - m);
                acc = fmaf(p, Whb[j * DD + lane], acc);
            }
        }
        acc /= lsum;
    } else {
        // all-masked row: softmax of equal NEG_BIG = uniform 1/N over ALL j
        for (int j = 0; j < NN; ++j) acc += Whb[j * DD + lane];
        acc *= (1.f / NN);
    }
    float o = (acc > 0.f) ? acc : expm1f(acc);
    out[row * DD + lane] = o;
}

extern "C" void kernel_launch(void* const* d_in, const int* in_sizes, int n_in,
                              void* d_out, int out_size, void* d_ws, size_t ws_size,
                              hipStream_t stream) {
    const float* ff      = (const float*)d_in[0];
    const int*   src_ips = (const int*)d_in[1];
    const int*   dst_ips = (const int*)d_in[2];
    // d_in[3] flow_volumes, d_in[4] emb, d_in[5..8] MLP params: adj weights are
    // products of sigmoids => strictly positive => only the >0 mask matters.
    const float* W  = (const float*)d_in[9];
    const float* a1 = (const float*)d_in[10];
    const float* a2 = (const float*)d_in[11];
    float* out = (float*)d_out;

    char* ws = (char*)d_ws;
    int* count          = (int*)ws;                                  // 16 KB
    unsigned int* mask  = (unsigned int*)(ws + (16 << 10));          // 512 KB
    float* f1           = (float*)(ws + (528 << 10));                // 16 KB
    float* f2           = (float*)(ws + (544 << 10));                // 16 KB
    int* bucket         = (int*)(ws + (1 << 20));                    // 4 MB
    float* Wh           = (float*)(ws + (5 << 20));                  // 1 MB

    // zero count + mask in one contiguous fill (they are adjacent)
    hipMemsetAsync(count, 0, (528 << 10), stream);

    build_kernel<<<BB * SS / 256, 256, 0, stream>>>(src_ips, dst_ips, count, bucket, mask);
    gather_transform_kernel<<<BB * NN / 4, 256, 0, stream>>>(ff, count, bucket, W, a1, a2, Wh, f1, f2);
    attn_kernel<<<BB * NN / 4, 256, 0, stream>>>(mask, f1, f2, Wh, out);
}